// Round 1
// baseline (1120.706 us; speedup 1.0000x reference)
//
#include <hip/hip_runtime.h>
#include <math.h>

// ---------------------------------------------------------------------------
// LongRec: fused recurrent recommender.
// B=256, S=200, D=U=128, NUM_CLASSES=50000, NUM_ITEMS=50000.
// Key simplification: alpha = softmax over a singleton axis == 1.0 exactly,
// so h_att = h_d and W_a / xa are dead code.
// Pipeline:
//   k1: gather xi/xt/xf + compute tg, fg (sigmoid), xr, xz, xh  (fp32 GEMV tiles)
//   k2: delta->decay, fdir, psi from tg/fg
//   k3: 200-step recurrence, one workgroup per batch row, W_h* columns in VGPRs
//   k4a: logits = h @ W_out + b_out
//   k4b: per-row online max/sum
//   k4c: normalize -> softmax output
// ---------------------------------------------------------------------------

#define B_  256
#define S_  200
#define U_  128
#define NC  50000
#define NTOK (B_ * S_)       // 51200
#define TOK_TILE 32

// ws layout (in floats)
#define PRE_OFF   0              // 51200*768 = 39321600 floats
#define PRE_SZ    (NTOK * 768)
#define TG_OFF    PRE_SZ         // 6553600 floats
#define FG_OFF    (PRE_SZ + NTOK * U_)
#define LOG_OFF   PRE_SZ         // aliases TG/FG (disjoint in time)
#define HF_OFF    (PRE_SZ + 13107200)      // 52428800
#define RMAX_OFF  (HF_OFF + B_ * U_)
#define RSUM_OFF  (RMAX_OFF + B_)

// PRE per-token layout: [decay(0) | xr(128) | xz(256) | xh(384) | fdir(512) | psi(640)]

__device__ __forceinline__ float sigmoidf_(float x) {
    if (x >= 0.f) { return 1.f / (1.f + expf(-x)); }
    float e = expf(x); return e / (1.f + e);
}
__device__ __forceinline__ float softplusf_(float x) {
    return fmaxf(x, 0.f) + log1pf(expf(-fabsf(x)));
}

// Accumulate 4-token x 4-u tile: a[i] += Xs[ttb+i][:] dot Wp[:, u4..u4+3]
__device__ __forceinline__ void mv_tile(const float (*Xs)[U_], const float* __restrict__ Wp,
                                        int ttb, int u4, float4 a[4]) {
#pragma unroll 4
    for (int k = 0; k < U_; ++k) {
        float4 w = *(const float4*)(Wp + k * U_ + u4);
#pragma unroll
        for (int i = 0; i < 4; ++i) {
            float x = Xs[ttb + i][k];
            a[i].x = fmaf(x, w.x, a[i].x);
            a[i].y = fmaf(x, w.y, a[i].y);
            a[i].z = fmaf(x, w.z, a[i].z);
            a[i].w = fmaf(x, w.w, a[i].w);
        }
    }
}
__device__ __forceinline__ void zero4(float4 a[4]) {
#pragma unroll
    for (int i = 0; i < 4; ++i) a[i] = make_float4(0.f, 0.f, 0.f, 0.f);
}

// ---------------------------------------------------------------------------
__global__ __launch_bounds__(256) void k1_precompute(
    const int* __restrict__ item, const int* __restrict__ tix, const int* __restrict__ frq,
    const float* __restrict__ Ei, const float* __restrict__ Et, const float* __restrict__ Ef,
    const float* __restrict__ W_xr, const float* __restrict__ b_r,
    const float* __restrict__ W_xz, const float* __restrict__ b_z,
    const float* __restrict__ W_xh, const float* __restrict__ b_h,
    const float* __restrict__ W_xtg, const float* __restrict__ W_tg, const float* __restrict__ b_tg,
    const float* __restrict__ W_xfg, const float* __restrict__ W_fg, const float* __restrict__ b_fg,
    float* __restrict__ PRE, float* __restrict__ TG, float* __restrict__ FG)
{
    __shared__ float xi[TOK_TILE][U_];
    __shared__ float xt[TOK_TILE][U_];
    __shared__ float xf[TOK_TILE][U_];
    const int t0 = blockIdx.x * TOK_TILE;
    const int tid = threadIdx.x;

    for (int idx = tid; idx < TOK_TILE * U_; idx += 256) {
        int tt = idx >> 7, k = idx & 127;
        int tok = t0 + tt;
        xi[tt][k] = Ei[(size_t)item[tok] * U_ + k];
        xt[tt][k] = Et[(size_t)tix[tok] * U_ + k];
        xf[tt][k] = Ef[(size_t)frq[tok] * U_ + k];
    }
    __syncthreads();

    const int u4  = (tid & 31) * 4;
    const int ttb = (tid >> 5) * 4;
    float4 a[4];

    // tg = sigmoid(xi@W_xtg + xt@W_tg + b_tg)
    zero4(a);
    mv_tile(xi, W_xtg, ttb, u4, a);
    mv_tile(xt, W_tg,  ttb, u4, a);
    {
        float4 bb = *(const float4*)&b_tg[u4];
#pragma unroll
        for (int i = 0; i < 4; ++i) {
            int tok = t0 + ttb + i;
            float4 v;
            v.x = sigmoidf_(a[i].x + bb.x); v.y = sigmoidf_(a[i].y + bb.y);
            v.z = sigmoidf_(a[i].z + bb.z); v.w = sigmoidf_(a[i].w + bb.w);
            *(float4*)&TG[(size_t)tok * U_ + u4] = v;
        }
    }
    // fg = sigmoid(xi@W_xfg + xf@W_fg + b_fg)
    zero4(a);
    mv_tile(xi, W_xfg, ttb, u4, a);
    mv_tile(xf, W_fg,  ttb, u4, a);
    {
        float4 bb = *(const float4*)&b_fg[u4];
#pragma unroll
        for (int i = 0; i < 4; ++i) {
            int tok = t0 + ttb + i;
            float4 v;
            v.x = sigmoidf_(a[i].x + bb.x); v.y = sigmoidf_(a[i].y + bb.y);
            v.z = sigmoidf_(a[i].z + bb.z); v.w = sigmoidf_(a[i].w + bb.w);
            *(float4*)&FG[(size_t)tok * U_ + u4] = v;
        }
    }
    // xr, xz, xh (pre-activation, stored into PRE)
    const float* Ws[3]  = { W_xr, W_xz, W_xh };
    const float* bs[3]  = { b_r, b_z, b_h };
    const int    off[3] = { 128, 256, 384 };
#pragma unroll
    for (int m = 0; m < 3; ++m) {
        zero4(a);
        mv_tile(xi, Ws[m], ttb, u4, a);
        float4 bb = *(const float4*)&bs[m][u4];
#pragma unroll
        for (int i = 0; i < 4; ++i) {
            int tok = t0 + ttb + i;
            float4 v;
            v.x = a[i].x + bb.x; v.y = a[i].y + bb.y;
            v.z = a[i].z + bb.z; v.w = a[i].w + bb.w;
            *(float4*)&PRE[(size_t)tok * 768 + off[m] + u4] = v;
        }
    }
}

// ---------------------------------------------------------------------------
__global__ __launch_bounds__(256) void k2_decay(
    const float* __restrict__ TG, const float* __restrict__ FG,
    const float* __restrict__ W_delta, const float* __restrict__ b_delta,
    const float* __restrict__ W_f_dir, const float* __restrict__ b_f_dir,
    const float* __restrict__ W_psi, const float* __restrict__ b_psi,
    float* __restrict__ PRE)
{
    __shared__ float tg[TOK_TILE][U_];
    __shared__ float fg[TOK_TILE][U_];
    const int t0 = blockIdx.x * TOK_TILE;
    const int tid = threadIdx.x;

    for (int idx = tid; idx < TOK_TILE * U_; idx += 256) {
        int tt = idx >> 7, k = idx & 127;
        int tok = t0 + tt;
        tg[tt][k] = TG[(size_t)tok * U_ + k];
        fg[tt][k] = FG[(size_t)tok * U_ + k];
    }
    __syncthreads();

    const int u4  = (tid & 31) * 4;
    const int ttb = (tid >> 5) * 4;
    float4 a[4];

    // decay = exp(-softplus([tg|fg] @ W_delta + b_delta))
    zero4(a);
    mv_tile(tg, W_delta,            ttb, u4, a);
    mv_tile(fg, W_delta + U_ * U_,  ttb, u4, a);
    {
        float4 bb = *(const float4*)&b_delta[u4];
#pragma unroll
        for (int i = 0; i < 4; ++i) {
            int tok = t0 + ttb + i;
            float4 v;
            v.x = expf(-softplusf_(a[i].x + bb.x));
            v.y = expf(-softplusf_(a[i].y + bb.y));
            v.z = expf(-softplusf_(a[i].z + bb.z));
            v.w = expf(-softplusf_(a[i].w + bb.w));
            *(float4*)&PRE[(size_t)tok * 768 + 0 + u4] = v;
        }
    }
    // fdir = fg @ W_f_dir + b_f_dir   (raw)
    zero4(a);
    mv_tile(fg, W_f_dir, ttb, u4, a);
    {
        float4 bb = *(const float4*)&b_f_dir[u4];
#pragma unroll
        for (int i = 0; i < 4; ++i) {
            int tok = t0 + ttb + i;
            float4 v;
            v.x = a[i].x + bb.x; v.y = a[i].y + bb.y;
            v.z = a[i].z + bb.z; v.w = a[i].w + bb.w;
            *(float4*)&PRE[(size_t)tok * 768 + 512 + u4] = v;
        }
    }
    // psi = sigmoid(fg @ W_psi + b_psi)
    zero4(a);
    mv_tile(fg, W_psi, ttb, u4, a);
    {
        float4 bb = *(const float4*)&b_psi[u4];
#pragma unroll
        for (int i = 0; i < 4; ++i) {
            int tok = t0 + ttb + i;
            float4 v;
            v.x = sigmoidf_(a[i].x + bb.x); v.y = sigmoidf_(a[i].y + bb.y);
            v.z = sigmoidf_(a[i].z + bb.z); v.w = sigmoidf_(a[i].w + bb.w);
            *(float4*)&PRE[(size_t)tok * 768 + 640 + u4] = v;
        }
    }
}

// ---------------------------------------------------------------------------
// Scan: one workgroup per batch row. 384 threads: g0 -> W_hr col, g1 -> W_hz,
// g2 -> W_hh, each thread holds one 128-deep weight column in VGPRs.
__global__ __launch_bounds__(384) void k3_scan(
    const float* __restrict__ PRE,
    const float* __restrict__ W_hr, const float* __restrict__ W_hz, const float* __restrict__ W_hh,
    float* __restrict__ h_out)
{
    const int b = blockIdx.x;
    const int tid = threadIdx.x;
    const int g = tid >> 7;      // 0,1,2
    const int u = tid & 127;

    const float* W = (g == 0) ? W_hr : ((g == 1) ? W_hz : W_hh);
    float wc[U_];
#pragma unroll
    for (int k = 0; k < U_; ++k) wc[k] = W[k * U_ + u];

    __shared__ __align__(16) float h[U_];
    __shared__ __align__(16) float hd[U_];
    __shared__ __align__(16) float rh[U_];
    __shared__ __align__(16) float zb[U_];
    if (tid < U_) h[tid] = 0.f;
    __syncthreads();

    const float* pre = PRE + (size_t)b * S_ * 768;
    for (int s = 0; s < S_; ++s) {
        const float* p = pre + (size_t)s * 768;
        float xr_u = 0.f, xz_u = 0.f, xh_u = 0.f, fd_u = 0.f, ps_u = 0.f, hdu = 0.f;
        if (g == 0) {
            float dec = p[u];
            xr_u = p[128 + u];
            hdu = dec * h[u];
            hd[u] = hdu;
        } else if (g == 1) {
            xz_u = p[256 + u];
        } else {
            xh_u = p[384 + u];
            fd_u = p[512 + u];
            ps_u = p[640 + u];
        }
        __syncthreads();   // hd ready

        if (g < 2) {
            float a0 = 0.f, a1 = 0.f, a2 = 0.f, a3 = 0.f;
#pragma unroll
            for (int kk = 0; kk < 32; ++kk) {
                float4 hv = *(const float4*)&hd[kk * 4];
                a0 = fmaf(hv.x, wc[4 * kk + 0], a0);
                a1 = fmaf(hv.y, wc[4 * kk + 1], a1);
                a2 = fmaf(hv.z, wc[4 * kk + 2], a2);
                a3 = fmaf(hv.w, wc[4 * kk + 3], a3);
            }
            float mv = (a0 + a1) + (a2 + a3);
            if (g == 0) {
                float r = sigmoidf_(xr_u + mv);
                rh[u] = r * hdu;
            } else {
                zb[u] = sigmoidf_(xz_u + mv);
            }
        }
        __syncthreads();   // rh, zb ready

        if (g == 2) {
            float a0 = 0.f, a1 = 0.f, a2 = 0.f, a3 = 0.f;
#pragma unroll
            for (int kk = 0; kk < 32; ++kk) {
                float4 hv = *(const float4*)&rh[kk * 4];
                a0 = fmaf(hv.x, wc[4 * kk + 0], a0);
                a1 = fmaf(hv.y, wc[4 * kk + 1], a1);
                a2 = fmaf(hv.z, wc[4 * kk + 2], a2);
                a3 = fmaf(hv.w, wc[4 * kk + 3], a3);
            }
            float mv2 = (a0 + a1) + (a2 + a3);
            float hb = tanhf(xh_u + mv2);
            float hf = tanhf(hb + fd_u);
            float hc = (1.f - ps_u) * hb + ps_u * hf;
            float z  = zb[u];
            float hdv = hd[u];
            h[u] = (1.f - z) * hdv + z * hc;   // alpha==1 -> h_att = h_d
        }
        __syncthreads();   // h ready for next step
    }
    if (tid < U_) h_out[(size_t)b * U_ + tid] = h[tid];
}

// ---------------------------------------------------------------------------
// logits = h @ W_out + b_out.  Block: 32 rows x 512 cols; thread: 16 rows x 4 cols.
__global__ __launch_bounds__(256) void k4a_logits(
    const float* __restrict__ h, const float* __restrict__ W_out,
    const float* __restrict__ b_out, float* __restrict__ logits)
{
    __shared__ float hs[32][U_];
    const int rb = blockIdx.y * 32;
    const int c0 = blockIdx.x * 512;
    const int tid = threadIdx.x;

    for (int idx = tid; idx < 32 * U_; idx += 256)
        hs[idx >> 7][idx & 127] = h[(size_t)(rb + (idx >> 7)) * U_ + (idx & 127)];
    __syncthreads();

    const int c  = c0 + (tid & 127) * 4;
    const int r0 = (tid >> 7) * 16;
    if (c >= NC) return;

    float4 acc[16];
#pragma unroll
    for (int i = 0; i < 16; ++i) acc[i] = make_float4(0.f, 0.f, 0.f, 0.f);

#pragma unroll 2
    for (int k = 0; k < U_; ++k) {
        float4 w = *(const float4*)&W_out[(size_t)k * NC + c];
#pragma unroll
        for (int i = 0; i < 16; ++i) {
            float x = hs[r0 + i][k];
            acc[i].x = fmaf(x, w.x, acc[i].x);
            acc[i].y = fmaf(x, w.y, acc[i].y);
            acc[i].z = fmaf(x, w.z, acc[i].z);
            acc[i].w = fmaf(x, w.w, acc[i].w);
        }
    }
    float4 bb = *(const float4*)&b_out[c];
#pragma unroll
    for (int i = 0; i < 16; ++i) {
        float4 v;
        v.x = acc[i].x + bb.x; v.y = acc[i].y + bb.y;
        v.z = acc[i].z + bb.z; v.w = acc[i].w + bb.w;
        *(float4*)&logits[(size_t)(rb + r0 + i) * NC + c] = v;
    }
}

// ---------------------------------------------------------------------------
__global__ __launch_bounds__(256) void k4b_rowstats(
    const float* __restrict__ logits, float* __restrict__ rmax, float* __restrict__ rsum)
{
    const int r = blockIdx.x;
    const int tid = threadIdx.x;
    const float* row = logits + (size_t)r * NC;

    float m = -INFINITY, s = 0.f;
    for (int c = tid; c < NC; c += 256) {
        float x = row[c];
        float mn = fmaxf(m, x);
        s = s * expf(m - mn) + expf(x - mn);
        m = mn;
    }
    __shared__ float sm[256], ss[256];
    sm[tid] = m; ss[tid] = s;
    __syncthreads();
    for (int off = 128; off > 0; off >>= 1) {
        if (tid < off) {
            float m2 = sm[tid + off], s2 = ss[tid + off];
            float M = fmaxf(sm[tid], m2);
            ss[tid] = ss[tid] * expf(sm[tid] - M) + s2 * expf(m2 - M);
            sm[tid] = M;
        }
        __syncthreads();
    }
    if (tid == 0) { rmax[r] = sm[0]; rsum[r] = ss[0]; }
}

__global__ __launch_bounds__(256) void k4c_norm(
    const float* __restrict__ logits, const float* __restrict__ rmax,
    const float* __restrict__ rsum, float* __restrict__ out)
{
    const int r = blockIdx.y;
    const int c = blockIdx.x * 256 + threadIdx.x;
    if (c < NC) {
        size_t i = (size_t)r * NC + c;
        out[i] = expf(logits[i] - rmax[r]) / rsum[r];
    }
}

// ---------------------------------------------------------------------------
extern "C" void kernel_launch(void* const* d_in, const int* in_sizes, int n_in,
                              void* d_out, int out_size, void* d_ws, size_t ws_size,
                              hipStream_t stream) {
    const int*   item   = (const int*)d_in[0];
    const int*   tix    = (const int*)d_in[1];
    const int*   frq    = (const int*)d_in[2];
    const float* Ei     = (const float*)d_in[3];
    const float* Et     = (const float*)d_in[4];
    const float* Ef     = (const float*)d_in[5];
    const float* W_xr   = (const float*)d_in[6];
    const float* W_hr   = (const float*)d_in[7];
    const float* b_r    = (const float*)d_in[8];
    const float* W_xz   = (const float*)d_in[9];
    const float* W_hz   = (const float*)d_in[10];
    const float* b_z    = (const float*)d_in[11];
    const float* W_xh   = (const float*)d_in[12];
    const float* W_hh   = (const float*)d_in[13];
    const float* b_h    = (const float*)d_in[14];
    const float* W_xtg  = (const float*)d_in[15];
    const float* W_tg   = (const float*)d_in[16];
    const float* b_tg   = (const float*)d_in[17];
    const float* W_xfg  = (const float*)d_in[18];
    const float* W_fg   = (const float*)d_in[19];
    const float* b_fg   = (const float*)d_in[20];
    const float* W_delta= (const float*)d_in[21];
    const float* b_delta= (const float*)d_in[22];
    const float* W_f_dir= (const float*)d_in[23];
    const float* b_f_dir= (const float*)d_in[24];
    const float* W_psi  = (const float*)d_in[25];
    const float* b_psi  = (const float*)d_in[26];
    // d_in[27] = W_a — mathematically dead (softmax over singleton axis == 1)
    const float* W_out  = (const float*)d_in[28];
    const float* b_out  = (const float*)d_in[29];
    float* out = (float*)d_out;

    float* ws   = (float*)d_ws;
    float* PRE  = ws + PRE_OFF;
    float* TG   = ws + TG_OFF;
    float* FG   = ws + FG_OFF;
    float* LOG  = ws + LOG_OFF;    // aliases TG/FG (disjoint lifetime)
    float* HF   = ws + HF_OFF;
    float* RMAX = ws + RMAX_OFF;
    float* RSUM = ws + RSUM_OFF;

    k1_precompute<<<NTOK / TOK_TILE, 256, 0, stream>>>(
        item, tix, frq, Ei, Et, Ef,
        W_xr, b_r, W_xz, b_z, W_xh, b_h,
        W_xtg, W_tg, b_tg, W_xfg, W_fg, b_fg,
        PRE, TG, FG);
    k2_decay<<<NTOK / TOK_TILE, 256, 0, stream>>>(
        TG, FG, W_delta, b_delta, W_f_dir, b_f_dir, W_psi, b_psi, PRE);
    k3_scan<<<B_, 384, 0, stream>>>(PRE, W_hr, W_hz, W_hh, HF);
    k4a_logits<<<dim3((NC + 511) / 512, B_ / 32), 256, 0, stream>>>(HF, W_out, b_out, LOG);
    k4b_rowstats<<<B_, 256, 0, stream>>>(LOG, RMAX, RSUM);
    k4c_norm<<<dim3((NC + 255) / 256, B_), 256, 0, stream>>>(LOG, RMAX, RSUM, out);
}

// Round 2
// 1007.013 us; speedup vs baseline: 1.1129x; 1.1129x over previous
//
#include <hip/hip_runtime.h>
#include <math.h>

// ---------------------------------------------------------------------------
// LongRec: fused recurrent recommender.  B=256, S=200, D=U=128, NC=50000.
// alpha = softmax over singleton axis == 1.0 -> h_att = h_d; W_a is dead.
// Pipeline:
//   k12: gather + ALL precompute matvecs (tg,fg in LDS; decay/xr/xz/xh/fdir/psi -> PRE)
//   k3 : 200-step recurrence, 1 wg/batch-row, W cols in VGPRs, light barriers,
//        next-step PRE prefetched across barriers (vmcnt left outstanding)
//   k4a/b/c: logits GEMM, row stats, softmax normalize
// ---------------------------------------------------------------------------

#define B_  256
#define S_  200
#define U_  128
#define NC  50000
#define NTOK (B_ * S_)       // 51200
#define TOK_TILE 32

// ws layout (in floats)
#define PRE_OFF   0
#define PRE_SZ    (NTOK * 768)            // 39321600 floats
#define LOG_OFF   PRE_SZ                  // logits (12.8M floats)
#define HF_OFF    (PRE_SZ + 13107200)
#define RMAX_OFF  (HF_OFF + B_ * U_)
#define RSUM_OFF  (RMAX_OFF + B_)

// PRE per-token layout: [decay(0) | xr(128) | xz(256) | xh(384) | fdir(512) | psi(640)]

__device__ __forceinline__ float sigmoidf_(float x) {
    if (x >= 0.f) { return 1.f / (1.f + expf(-x)); }
    float e = expf(x); return e / (1.f + e);
}
__device__ __forceinline__ float softplusf_(float x) {
    return fmaxf(x, 0.f) + log1pf(expf(-fabsf(x)));
}
// Workgroup barrier that only drains LDS (lgkmcnt), leaving global loads
// (vmcnt) in flight — lets PRE prefetch span the whole recurrence step.
__device__ __forceinline__ void bar_lds() {
    asm volatile("s_waitcnt lgkmcnt(0)\n\ts_barrier" ::: "memory");
}

// Accumulate 4-token x 4-u tile with float4 LDS reads.
__device__ __forceinline__ void mv_tile(const float (*Xs)[U_], const float* __restrict__ Wp,
                                        int ttb, int u4, float4 a[4]) {
#pragma unroll 2
    for (int k = 0; k < U_; k += 4) {
        float xv[4][4];
#pragma unroll
        for (int i = 0; i < 4; ++i)
            *(float4*)&xv[i][0] = *(const float4*)&Xs[ttb + i][k];
#pragma unroll
        for (int j = 0; j < 4; ++j) {
            float4 w = *(const float4*)(Wp + (size_t)(k + j) * U_ + u4);
#pragma unroll
            for (int i = 0; i < 4; ++i) {
                float x = xv[i][j];
                a[i].x = fmaf(x, w.x, a[i].x);
                a[i].y = fmaf(x, w.y, a[i].y);
                a[i].z = fmaf(x, w.z, a[i].z);
                a[i].w = fmaf(x, w.w, a[i].w);
            }
        }
    }
}
__device__ __forceinline__ void zero4(float4 a[4]) {
#pragma unroll
    for (int i = 0; i < 4; ++i) a[i] = make_float4(0.f, 0.f, 0.f, 0.f);
}

// ---------------------------------------------------------------------------
// Fused precompute: gathers + 11 matvecs. xb holds xt then tg; xc holds xf then fg.
__global__ __launch_bounds__(256) void k12_precompute(
    const int* __restrict__ item, const int* __restrict__ tix, const int* __restrict__ frq,
    const float* __restrict__ Ei, const float* __restrict__ Et, const float* __restrict__ Ef,
    const float* __restrict__ W_xr, const float* __restrict__ b_r,
    const float* __restrict__ W_xz, const float* __restrict__ b_z,
    const float* __restrict__ W_xh, const float* __restrict__ b_h,
    const float* __restrict__ W_xtg, const float* __restrict__ W_tg, const float* __restrict__ b_tg,
    const float* __restrict__ W_xfg, const float* __restrict__ W_fg, const float* __restrict__ b_fg,
    const float* __restrict__ W_delta, const float* __restrict__ b_delta,
    const float* __restrict__ W_f_dir, const float* __restrict__ b_f_dir,
    const float* __restrict__ W_psi, const float* __restrict__ b_psi,
    float* __restrict__ PRE)
{
    __shared__ float xi[TOK_TILE][U_];
    __shared__ float xb[TOK_TILE][U_];   // xt, later tg
    __shared__ float xc[TOK_TILE][U_];   // xf, later fg
    const int t0 = blockIdx.x * TOK_TILE;
    const int tid = threadIdx.x;

    for (int idx = tid; idx < TOK_TILE * U_; idx += 256) {
        int tt = idx >> 7, k = idx & 127;
        int tok = t0 + tt;
        xi[tt][k] = Ei[(size_t)item[tok] * U_ + k];
        xb[tt][k] = Et[(size_t)tix[tok] * U_ + k];
        xc[tt][k] = Ef[(size_t)frq[tok] * U_ + k];
    }
    __syncthreads();

    const int u4  = (tid & 31) * 4;
    const int ttb = (tid >> 5) * 4;

    // tg = sigmoid(xi@W_xtg + xt@W_tg + b), fg = sigmoid(xi@W_xfg + xf@W_fg + b)
    float4 tga[4], fga[4];
    zero4(tga);
    mv_tile(xi, W_xtg, ttb, u4, tga);
    mv_tile(xb, W_tg,  ttb, u4, tga);
    zero4(fga);
    mv_tile(xi, W_xfg, ttb, u4, fga);
    mv_tile(xc, W_fg,  ttb, u4, fga);
    __syncthreads();   // everyone done reading xb/xc

    {
        float4 bt = *(const float4*)&b_tg[u4];
        float4 bf = *(const float4*)&b_fg[u4];
#pragma unroll
        for (int i = 0; i < 4; ++i) {
            xb[ttb + i][u4 + 0] = sigmoidf_(tga[i].x + bt.x);
            xb[ttb + i][u4 + 1] = sigmoidf_(tga[i].y + bt.y);
            xb[ttb + i][u4 + 2] = sigmoidf_(tga[i].z + bt.z);
            xb[ttb + i][u4 + 3] = sigmoidf_(tga[i].w + bt.w);
            xc[ttb + i][u4 + 0] = sigmoidf_(fga[i].x + bf.x);
            xc[ttb + i][u4 + 1] = sigmoidf_(fga[i].y + bf.y);
            xc[ttb + i][u4 + 2] = sigmoidf_(fga[i].z + bf.z);
            xc[ttb + i][u4 + 3] = sigmoidf_(fga[i].w + bf.w);
        }
    }
    __syncthreads();   // tg/fg ready

    float4 a[4];
    // xr, xz, xh (pre-activation)
    const float* Ws[3]  = { W_xr, W_xz, W_xh };
    const float* bs[3]  = { b_r, b_z, b_h };
    const int    off[3] = { 128, 256, 384 };
#pragma unroll
    for (int m = 0; m < 3; ++m) {
        zero4(a);
        mv_tile(xi, Ws[m], ttb, u4, a);
        float4 bb = *(const float4*)&bs[m][u4];
#pragma unroll
        for (int i = 0; i < 4; ++i) {
            int tok = t0 + ttb + i;
            float4 v;
            v.x = a[i].x + bb.x; v.y = a[i].y + bb.y;
            v.z = a[i].z + bb.z; v.w = a[i].w + bb.w;
            *(float4*)&PRE[(size_t)tok * 768 + off[m] + u4] = v;
        }
    }
    // decay = exp(-softplus([tg|fg]@W_delta + b))
    zero4(a);
    mv_tile(xb, W_delta,           ttb, u4, a);
    mv_tile(xc, W_delta + U_ * U_, ttb, u4, a);
    {
        float4 bb = *(const float4*)&b_delta[u4];
#pragma unroll
        for (int i = 0; i < 4; ++i) {
            int tok = t0 + ttb + i;
            float4 v;
            v.x = expf(-softplusf_(a[i].x + bb.x));
            v.y = expf(-softplusf_(a[i].y + bb.y));
            v.z = expf(-softplusf_(a[i].z + bb.z));
            v.w = expf(-softplusf_(a[i].w + bb.w));
            *(float4*)&PRE[(size_t)tok * 768 + 0 + u4] = v;
        }
    }
    // fdir = fg@W_f_dir + b
    zero4(a);
    mv_tile(xc, W_f_dir, ttb, u4, a);
    {
        float4 bb = *(const float4*)&b_f_dir[u4];
#pragma unroll
        for (int i = 0; i < 4; ++i) {
            int tok = t0 + ttb + i;
            float4 v;
            v.x = a[i].x + bb.x; v.y = a[i].y + bb.y;
            v.z = a[i].z + bb.z; v.w = a[i].w + bb.w;
            *(float4*)&PRE[(size_t)tok * 768 + 512 + u4] = v;
        }
    }
    // psi = sigmoid(fg@W_psi + b)
    zero4(a);
    mv_tile(xc, W_psi, ttb, u4, a);
    {
        float4 bb = *(const float4*)&b_psi[u4];
#pragma unroll
        for (int i = 0; i < 4; ++i) {
            int tok = t0 + ttb + i;
            float4 v;
            v.x = sigmoidf_(a[i].x + bb.x); v.y = sigmoidf_(a[i].y + bb.y);
            v.z = sigmoidf_(a[i].z + bb.z); v.w = sigmoidf_(a[i].w + bb.w);
            *(float4*)&PRE[(size_t)tok * 768 + 640 + u4] = v;
        }
    }
}

// ---------------------------------------------------------------------------
// Scan: one workgroup per batch row. 384 threads: g0->W_hr, g1->W_hz, g2->W_hh;
// each thread holds one 128-deep weight column in VGPRs (launch_bounds(384,2)
// caps at 256 VGPR so wc[] does NOT spill). Next-step PRE values prefetched
// with vmcnt left outstanding across the lgkm-only barriers.
__global__ __launch_bounds__(384, 2) void k3_scan(
    const float* __restrict__ PRE,
    const float* __restrict__ W_hr, const float* __restrict__ W_hz, const float* __restrict__ W_hh,
    float* __restrict__ h_out)
{
    const int b = blockIdx.x;
    const int tid = threadIdx.x;
    const int g = tid >> 7;      // 0,1,2
    const int u = tid & 127;

    const float* W = (g == 0) ? W_hr : ((g == 1) ? W_hz : W_hh);
    float wc[U_];
#pragma unroll
    for (int k = 0; k < U_; ++k) wc[k] = W[(size_t)k * U_ + u];

    __shared__ __align__(16) float h[U_];
    __shared__ __align__(16) float hd[U_];
    __shared__ __align__(16) float rh[U_];
    __shared__ __align__(16) float zb[U_];
    if (tid < U_) h[tid] = 0.f;

    const float* pre = PRE + (size_t)b * S_ * 768;
    float c0 = 0.f, c1 = 0.f, c2 = 0.f;
    {
        const float* p = pre;
        if (g == 0)      { c0 = p[u];       c1 = p[128 + u]; }
        else if (g == 1) { c0 = p[256 + u]; }
        else             { c0 = p[384 + u]; c1 = p[512 + u]; c2 = p[640 + u]; }
    }
    bar_lds();

    for (int s = 0; s < S_; ++s) {
        float hdu = 0.f;
        if (g == 0) { hdu = c0 * h[u]; hd[u] = hdu; }

        // prefetch step s+1 (stays in flight across the barriers below)
        float n0 = 0.f, n1 = 0.f, n2 = 0.f;
        if (s + 1 < S_) {
            const float* p = pre + (size_t)(s + 1) * 768;
            if (g == 0)      { n0 = p[u];       n1 = p[128 + u]; }
            else if (g == 1) { n0 = p[256 + u]; }
            else             { n0 = p[384 + u]; n1 = p[512 + u]; n2 = p[640 + u]; }
        }
        bar_lds();   // hd ready

        if (g < 2) {
            float a0 = 0.f, a1 = 0.f, a2 = 0.f, a3 = 0.f;
#pragma unroll
            for (int kk = 0; kk < 32; ++kk) {
                float4 hv = *(const float4*)&hd[kk * 4];
                a0 = fmaf(hv.x, wc[4 * kk + 0], a0);
                a1 = fmaf(hv.y, wc[4 * kk + 1], a1);
                a2 = fmaf(hv.z, wc[4 * kk + 2], a2);
                a3 = fmaf(hv.w, wc[4 * kk + 3], a3);
            }
            float mv = (a0 + a1) + (a2 + a3);
            if (g == 0) {
                float r = sigmoidf_(c1 + mv);
                rh[u] = r * hdu;
            } else {
                zb[u] = sigmoidf_(c0 + mv);
            }
        }
        bar_lds();   // rh, zb ready

        if (g == 2) {
            float a0 = 0.f, a1 = 0.f, a2 = 0.f, a3 = 0.f;
#pragma unroll
            for (int kk = 0; kk < 32; ++kk) {
                float4 hv = *(const float4*)&rh[kk * 4];
                a0 = fmaf(hv.x, wc[4 * kk + 0], a0);
                a1 = fmaf(hv.y, wc[4 * kk + 1], a1);
                a2 = fmaf(hv.z, wc[4 * kk + 2], a2);
                a3 = fmaf(hv.w, wc[4 * kk + 3], a3);
            }
            float mv2 = (a0 + a1) + (a2 + a3);
            float hb = tanhf(c0 + mv2);
            float hf = tanhf(hb + c1);
            float hc = (1.f - c2) * hb + c2 * hf;
            float z  = zb[u];
            h[u] = (1.f - z) * hd[u] + z * hc;   // alpha==1 -> h_att = h_d
        }
        bar_lds();   // h ready for next step

        c0 = n0; c1 = n1; c2 = n2;
    }
    if (tid < U_) h_out[(size_t)b * U_ + tid] = h[tid];
}

// ---------------------------------------------------------------------------
__global__ __launch_bounds__(256) void k4a_logits(
    const float* __restrict__ h, const float* __restrict__ W_out,
    const float* __restrict__ b_out, float* __restrict__ logits)
{
    __shared__ float hs[32][U_];
    const int rb = blockIdx.y * 32;
    const int c0 = blockIdx.x * 512;
    const int tid = threadIdx.x;

    for (int idx = tid; idx < 32 * U_; idx += 256)
        hs[idx >> 7][idx & 127] = h[(size_t)(rb + (idx >> 7)) * U_ + (idx & 127)];
    __syncthreads();

    const int c  = c0 + (tid & 127) * 4;
    const int r0 = (tid >> 7) * 16;
    if (c >= NC) return;

    float4 acc[16];
#pragma unroll
    for (int i = 0; i < 16; ++i) acc[i] = make_float4(0.f, 0.f, 0.f, 0.f);

#pragma unroll 2
    for (int k = 0; k < U_; ++k) {
        float4 w = *(const float4*)&W_out[(size_t)k * NC + c];
#pragma unroll
        for (int i = 0; i < 16; ++i) {
            float x = hs[r0 + i][k];
            acc[i].x = fmaf(x, w.x, acc[i].x);
            acc[i].y = fmaf(x, w.y, acc[i].y);
            acc[i].z = fmaf(x, w.z, acc[i].z);
            acc[i].w = fmaf(x, w.w, acc[i].w);
        }
    }
    float4 bb = *(const float4*)&b_out[c];
#pragma unroll
    for (int i = 0; i < 16; ++i) {
        float4 v;
        v.x = acc[i].x + bb.x; v.y = acc[i].y + bb.y;
        v.z = acc[i].z + bb.z; v.w = acc[i].w + bb.w;
        *(float4*)&logits[(size_t)(rb + r0 + i) * NC + c] = v;
    }
}

// ---------------------------------------------------------------------------
__global__ __launch_bounds__(256) void k4b_rowstats(
    const float* __restrict__ logits, float* __restrict__ rmax, float* __restrict__ rsum)
{
    const int r = blockIdx.x;
    const int tid = threadIdx.x;
    const float* row = logits + (size_t)r * NC;

    float m = -INFINITY, s = 0.f;
    for (int c = tid; c < NC; c += 256) {
        float x = row[c];
        float mn = fmaxf(m, x);
        s = s * expf(m - mn) + expf(x - mn);
        m = mn;
    }
    __shared__ float sm[256], ss[256];
    sm[tid] = m; ss[tid] = s;
    __syncthreads();
    for (int off = 128; off > 0; off >>= 1) {
        if (tid < off) {
            float m2 = sm[tid + off], s2 = ss[tid + off];
            float M = fmaxf(sm[tid], m2);
            ss[tid] = ss[tid] * expf(sm[tid] - M) + s2 * expf(m2 - M);
            sm[tid] = M;
        }
        __syncthreads();
    }
    if (tid == 0) { rmax[r] = sm[0]; rsum[r] = ss[0]; }
}

__global__ __launch_bounds__(256) void k4c_norm(
    const float* __restrict__ logits, const float* __restrict__ rmax,
    const float* __restrict__ rsum, float* __restrict__ out)
{
    const int r = blockIdx.y;
    const int c = blockIdx.x * 256 + threadIdx.x;
    if (c < NC) {
        size_t i = (size_t)r * NC + c;
        out[i] = expf(logits[i] - rmax[r]) / rsum[r];
    }
}

// ---------------------------------------------------------------------------
extern "C" void kernel_launch(void* const* d_in, const int* in_sizes, int n_in,
                              void* d_out, int out_size, void* d_ws, size_t ws_size,
                              hipStream_t stream) {
    const int*   item   = (const int*)d_in[0];
    const int*   tix    = (const int*)d_in[1];
    const int*   frq    = (const int*)d_in[2];
    const float* Ei     = (const float*)d_in[3];
    const float* Et     = (const float*)d_in[4];
    const float* Ef     = (const float*)d_in[5];
    const float* W_xr   = (const float*)d_in[6];
    const float* W_hr   = (const float*)d_in[7];
    const float* b_r    = (const float*)d_in[8];
    const float* W_xz   = (const float*)d_in[9];
    const float* W_hz   = (const float*)d_in[10];
    const float* b_z    = (const float*)d_in[11];
    const float* W_xh   = (const float*)d_in[12];
    const float* W_hh   = (const float*)d_in[13];
    const float* b_h    = (const float*)d_in[14];
    const float* W_xtg  = (const float*)d_in[15];
    const float* W_tg   = (const float*)d_in[16];
    const float* b_tg   = (const float*)d_in[17];
    const float* W_xfg  = (const float*)d_in[18];
    const float* W_fg   = (const float*)d_in[19];
    const float* b_fg   = (const float*)d_in[20];
    const float* W_delta= (const float*)d_in[21];
    const float* b_delta= (const float*)d_in[22];
    const float* W_f_dir= (const float*)d_in[23];
    const float* b_f_dir= (const float*)d_in[24];
    const float* W_psi  = (const float*)d_in[25];
    const float* b_psi  = (const float*)d_in[26];
    // d_in[27] = W_a — dead (softmax over singleton axis == 1)
    const float* W_out  = (const float*)d_in[28];
    const float* b_out  = (const float*)d_in[29];
    float* out = (float*)d_out;

    float* ws   = (float*)d_ws;
    float* PRE  = ws + PRE_OFF;
    float* LOG  = ws + LOG_OFF;
    float* HF   = ws + HF_OFF;
    float* RMAX = ws + RMAX_OFF;
    float* RSUM = ws + RSUM_OFF;

    k12_precompute<<<NTOK / TOK_TILE, 256, 0, stream>>>(
        item, tix, frq, Ei, Et, Ef,
        W_xr, b_r, W_xz, b_z, W_xh, b_h,
        W_xtg, W_tg, b_tg, W_xfg, W_fg, b_fg,
        W_delta, b_delta, W_f_dir, b_f_dir, W_psi, b_psi,
        PRE);
    k3_scan<<<B_, 384, 0, stream>>>(PRE, W_hr, W_hz, W_hh, HF);
    k4a_logits<<<dim3((NC + 511) / 512, B_ / 32), 256, 0, stream>>>(HF, W_out, b_out, LOG);
    k4b_rowstats<<<B_, 256, 0, stream>>>(LOG, RMAX, RSUM);
    k4c_norm<<<dim3((NC + 255) / 256, B_), 256, 0, stream>>>(LOG, RMAX, RSUM, out);
}

// Round 3
// 921.407 us; speedup vs baseline: 1.2163x; 1.0929x over previous
//
#include <hip/hip_runtime.h>
#include <math.h>

// ---------------------------------------------------------------------------
// LongRec.  B=256, S=200, D=U=128, NC=50000.
// alpha = softmax over singleton axis == 1.0 -> h_att = h_d; W_a is dead.
// Pipeline:
//   k0 : weights fp32 -> bf16, k-swizzled [k/32][n][32] for contiguous B-frags
//   k12: MFMA precompute. 64 tok/block, 4 waves, wave-local LDS (no barriers).
//        tg/fg kept in LDS bf16 (A-frag layout); decay/xr/xz/xh/fdir/psi -> PRE fp32
//   k3 : 200-step recurrence, 1 wg/row, W cols in VGPRs, lgkm-only barriers
//   k4a/b/c: logits GEMM, row stats, softmax normalize
// ---------------------------------------------------------------------------

#define B_  256
#define S_  200
#define U_  128
#define NC  50000
#define NTOK (B_ * S_)       // 51200

// ws layout (in floats)
#define PRE_OFF   0
#define PRE_SZ    (NTOK * 768)            // 39321600 floats
#define LOG_OFF   PRE_SZ                  // logits: 12.8M floats
#define WSWZ_OFF  (PRE_SZ + 12800000)     // bf16 weights: 12*16384 ushort = 98304 floats
#define HF_OFF    (PRE_SZ + 13107200)
#define RMAX_OFF  (HF_OFF + B_ * U_)
#define RSUM_OFF  (RMAX_OFF + B_)

// PRE per-token layout: [decay(0) | xr(128) | xz(256) | xh(384) | fdir(512) | psi(640)]

typedef float  float4v  __attribute__((ext_vector_type(4)));
typedef short  short8v  __attribute__((ext_vector_type(8)));

__device__ __forceinline__ float sigmoidf_(float x) {
    if (x >= 0.f) { return 1.f / (1.f + expf(-x)); }
    float e = expf(x); return e / (1.f + e);
}
__device__ __forceinline__ float softplusf_(float x) {
    return fmaxf(x, 0.f) + log1pf(expf(-fabsf(x)));
}
__device__ __forceinline__ unsigned short f2bf(float f) {   // RNE
    unsigned int u = __float_as_uint(f);
    u = (u + 0x7fffu + ((u >> 16) & 1u)) >> 16;
    return (unsigned short)u;
}
__device__ __forceinline__ unsigned int pack2bf(float a, float b) {
    return (unsigned int)f2bf(a) | ((unsigned int)f2bf(b) << 16);
}
// Barrier draining only LDS (lgkmcnt) — global prefetches stay in flight.
__device__ __forceinline__ void bar_lds() {
    asm volatile("s_waitcnt lgkmcnt(0)\n\ts_barrier" ::: "memory");
}

// ---------------------------------------------------------------------------
// k0: 12 x [128][128] fp32 -> bf16 swizzled  dst[((k>>5)*128 + n)*32 + (k&31)]
__global__ __launch_bounds__(256) void k0_wconv(
    const float* s0, const float* s1, const float* s2, const float* s3,
    const float* s4, const float* s5, const float* s6, const float* s7,
    const float* s8, const float* s9, const float* s10, const float* s11,
    unsigned short* __restrict__ dst)
{
    const float* srcs[12] = { s0,s1,s2,s3,s4,s5,s6,s7,s8,s9,s10,s11 };
    const float* S = srcs[blockIdx.x];
    unsigned short* D = dst + (size_t)blockIdx.x * 16384;
    for (int i = threadIdx.x; i < 16384; i += 256) {
        int k5 = i & 31, n = (i >> 5) & 127, kb = i >> 12;
        D[i] = f2bf(S[(size_t)(kb * 32 + k5) * 128 + n]);
    }
}

// ---------------------------------------------------------------------------
// MFMA helpers.  A-frag: lane holds A[m0 + (lane&15)][kb*32 + quad*8 + j].
// B-frag (swizzled W): lane holds W[kb*32 + quad*8 + j][nt*16 + (lane&15)].
// C/D: col = lane&15, row = quad*4 + reg.
__device__ __forceinline__ void gemm_k128(const unsigned short (*A)[136],
                                          int m0, int l16, int quad,
                                          const unsigned short* __restrict__ Wm,
                                          float4v acc[8]) {
#pragma unroll
    for (int kb = 0; kb < 4; ++kb) {
        short8v av = *(const short8v*)&A[m0 + l16][kb * 32 + quad * 8];
#pragma unroll
        for (int nt = 0; nt < 8; ++nt) {
            short8v bv = *(const short8v*)(Wm + (((kb * 128) + nt * 16 + l16) * 32 + quad * 8));
            acc[nt] = __builtin_amdgcn_mfma_f32_16x16x32_bf16(av, bv, acc[nt], 0, 0, 0);
        }
    }
}
__device__ __forceinline__ void zero8(float4v acc[8]) {
#pragma unroll
    for (int i = 0; i < 8; ++i) acc[i] = (float4v)0.0f;
}

// ---------------------------------------------------------------------------
// k12: fused MFMA precompute.  grid = NTOK/64, block = 256 (4 waves).
__global__ __launch_bounds__(256) void k12_precompute(
    const int* __restrict__ item, const int* __restrict__ tix, const int* __restrict__ frq,
    const float* __restrict__ Ei, const float* __restrict__ Et, const float* __restrict__ Ef,
    const float* __restrict__ b_r, const float* __restrict__ b_z, const float* __restrict__ b_h,
    const float* __restrict__ b_tg, const float* __restrict__ b_fg,
    const float* __restrict__ b_delta, const float* __restrict__ b_f_dir, const float* __restrict__ b_psi,
    const unsigned short* __restrict__ WZ,
    float* __restrict__ PRE)
{
    __shared__ unsigned short Axi[64][136];   // xi
    __shared__ unsigned short Axb[64][136];   // xt -> tg
    __shared__ unsigned short Axc[64][136];   // xf -> fg

    const int t0  = blockIdx.x * 64;
    const int tid = threadIdx.x;

    // Staging: thread t -> row t>>2 (rows are WAVE-LOCAL: wave w stages rows
    // 16w..16w+15 and only ever reads/writes those rows => no barriers needed).
    {
        const int row  = tid >> 2;
        const int part = tid & 3;
        const int tok  = t0 + row;
        const float* pei = Ei + (size_t)item[tok] * U_ + part * 32;
        const float* pet = Et + (size_t)tix[tok]  * U_ + part * 32;
        const float* pef = Ef + (size_t)frq[tok]  * U_ + part * 32;
#pragma unroll
        for (int i = 0; i < 8; ++i) {
            float4 v = *(const float4*)(pei + i * 4);
            *(uint2*)&Axi[row][part * 32 + i * 4] = make_uint2(pack2bf(v.x, v.y), pack2bf(v.z, v.w));
            v = *(const float4*)(pet + i * 4);
            *(uint2*)&Axb[row][part * 32 + i * 4] = make_uint2(pack2bf(v.x, v.y), pack2bf(v.z, v.w));
            v = *(const float4*)(pef + i * 4);
            *(uint2*)&Axc[row][part * 32 + i * 4] = make_uint2(pack2bf(v.x, v.y), pack2bf(v.z, v.w));
        }
    }

    const int lane = tid & 63;
    const int wid  = tid >> 6;
    const int quad = lane >> 4;
    const int l16  = lane & 15;
    const int m0   = wid * 16;

    const unsigned short* WM0  = WZ;                 // W_xtg
    const unsigned short* WM1  = WZ + 1  * 16384;    // W_tg
    const unsigned short* WM2  = WZ + 2  * 16384;    // W_xfg
    const unsigned short* WM3  = WZ + 3  * 16384;    // W_fg
    const unsigned short* WM4  = WZ + 4  * 16384;    // W_xr
    const unsigned short* WM5  = WZ + 5  * 16384;    // W_xz
    const unsigned short* WM6  = WZ + 6  * 16384;    // W_xh
    const unsigned short* WM7  = WZ + 7  * 16384;    // W_delta top (tg rows)
    const unsigned short* WM8  = WZ + 8  * 16384;    // W_delta bot (fg rows)
    const unsigned short* WM9  = WZ + 9  * 16384;    // W_f_dir
    const unsigned short* WM10 = WZ + 10 * 16384;    // W_psi

    float4v acc[8];

    // ---- tg = sigmoid(xi@W_xtg + xt@W_tg + b_tg) -> Axb (bf16, A-layout) ----
    zero8(acc);
    gemm_k128(Axi, m0, l16, quad, WM0, acc);
    gemm_k128(Axb, m0, l16, quad, WM1, acc);
#pragma unroll
    for (int nt = 0; nt < 8; ++nt) {
        int n = nt * 16 + l16;
        float bb = b_tg[n];
#pragma unroll
        for (int r = 0; r < 4; ++r)
            Axb[m0 + quad * 4 + r][n] = f2bf(sigmoidf_(acc[nt][r] + bb));
    }
    // ---- fg = sigmoid(xi@W_xfg + xf@W_fg + b_fg) -> Axc ----
    zero8(acc);
    gemm_k128(Axi, m0, l16, quad, WM2, acc);
    gemm_k128(Axc, m0, l16, quad, WM3, acc);
#pragma unroll
    for (int nt = 0; nt < 8; ++nt) {
        int n = nt * 16 + l16;
        float bb = b_fg[n];
#pragma unroll
        for (int r = 0; r < 4; ++r)
            Axc[m0 + quad * 4 + r][n] = f2bf(sigmoidf_(acc[nt][r] + bb));
    }

    const int tokbase = t0 + m0 + quad * 4;

    // ---- xr, xz, xh ----
    {
        const unsigned short* Wx[3] = { WM4, WM5, WM6 };
        const float* bx[3] = { b_r, b_z, b_h };
        const int    off[3] = { 128, 256, 384 };
#pragma unroll
        for (int m = 0; m < 3; ++m) {
            zero8(acc);
            gemm_k128(Axi, m0, l16, quad, Wx[m], acc);
#pragma unroll
            for (int nt = 0; nt < 8; ++nt) {
                int n = nt * 16 + l16;
                float bb = bx[m][n];
#pragma unroll
                for (int r = 0; r < 4; ++r)
                    PRE[(size_t)(tokbase + r) * 768 + off[m] + n] = acc[nt][r] + bb;
            }
        }
    }
    // ---- decay = exp(-softplus([tg|fg]@W_delta + b_delta)) ----
    zero8(acc);
    gemm_k128(Axb, m0, l16, quad, WM7, acc);
    gemm_k128(Axc, m0, l16, quad, WM8, acc);
#pragma unroll
    for (int nt = 0; nt < 8; ++nt) {
        int n = nt * 16 + l16;
        float bb = b_delta[n];
#pragma unroll
        for (int r = 0; r < 4; ++r)
            PRE[(size_t)(tokbase + r) * 768 + 0 + n] = expf(-softplusf_(acc[nt][r] + bb));
    }
    // ---- fdir = fg@W_f_dir + b ----
    zero8(acc);
    gemm_k128(Axc, m0, l16, quad, WM9, acc);
#pragma unroll
    for (int nt = 0; nt < 8; ++nt) {
        int n = nt * 16 + l16;
        float bb = b_f_dir[n];
#pragma unroll
        for (int r = 0; r < 4; ++r)
            PRE[(size_t)(tokbase + r) * 768 + 512 + n] = acc[nt][r] + bb;
    }
    // ---- psi = sigmoid(fg@W_psi + b) ----
    zero8(acc);
    gemm_k128(Axc, m0, l16, quad, WM10, acc);
#pragma unroll
    for (int nt = 0; nt < 8; ++nt) {
        int n = nt * 16 + l16;
        float bb = b_psi[n];
#pragma unroll
        for (int r = 0; r < 4; ++r)
            PRE[(size_t)(tokbase + r) * 768 + 640 + n] = sigmoidf_(acc[nt][r] + bb);
    }
}

// ---------------------------------------------------------------------------
// Scan: one workgroup per batch row (unchanged from R1).
__global__ __launch_bounds__(384, 2) void k3_scan(
    const float* __restrict__ PRE,
    const float* __restrict__ W_hr, const float* __restrict__ W_hz, const float* __restrict__ W_hh,
    float* __restrict__ h_out)
{
    const int b = blockIdx.x;
    const int tid = threadIdx.x;
    const int g = tid >> 7;      // 0,1,2
    const int u = tid & 127;

    const float* W = (g == 0) ? W_hr : ((g == 1) ? W_hz : W_hh);
    float wc[U_];
#pragma unroll
    for (int k = 0; k < U_; ++k) wc[k] = W[(size_t)k * U_ + u];

    __shared__ __align__(16) float h[U_];
    __shared__ __align__(16) float hd[U_];
    __shared__ __align__(16) float rh[U_];
    __shared__ __align__(16) float zb[U_];
    if (tid < U_) h[tid] = 0.f;

    const float* pre = PRE + (size_t)b * S_ * 768;
    float c0 = 0.f, c1 = 0.f, c2 = 0.f;
    {
        const float* p = pre;
        if (g == 0)      { c0 = p[u];       c1 = p[128 + u]; }
        else if (g == 1) { c0 = p[256 + u]; }
        else             { c0 = p[384 + u]; c1 = p[512 + u]; c2 = p[640 + u]; }
    }
    bar_lds();

    for (int s = 0; s < S_; ++s) {
        float hdu = 0.f;
        if (g == 0) { hdu = c0 * h[u]; hd[u] = hdu; }

        float n0 = 0.f, n1 = 0.f, n2 = 0.f;
        if (s + 1 < S_) {
            const float* p = pre + (size_t)(s + 1) * 768;
            if (g == 0)      { n0 = p[u];       n1 = p[128 + u]; }
            else if (g == 1) { n0 = p[256 + u]; }
            else             { n0 = p[384 + u]; n1 = p[512 + u]; n2 = p[640 + u]; }
        }
        bar_lds();   // hd ready

        if (g < 2) {
            float a0 = 0.f, a1 = 0.f, a2 = 0.f, a3 = 0.f;
#pragma unroll
            for (int kk = 0; kk < 32; ++kk) {
                float4 hv = *(const float4*)&hd[kk * 4];
                a0 = fmaf(hv.x, wc[4 * kk + 0], a0);
                a1 = fmaf(hv.y, wc[4 * kk + 1], a1);
                a2 = fmaf(hv.z, wc[4 * kk + 2], a2);
                a3 = fmaf(hv.w, wc[4 * kk + 3], a3);
            }
            float mv = (a0 + a1) + (a2 + a3);
            if (g == 0) {
                float r = sigmoidf_(c1 + mv);
                rh[u] = r * hdu;
            } else {
                zb[u] = sigmoidf_(c0 + mv);
            }
        }
        bar_lds();   // rh, zb ready

        if (g == 2) {
            float a0 = 0.f, a1 = 0.f, a2 = 0.f, a3 = 0.f;
#pragma unroll
            for (int kk = 0; kk < 32; ++kk) {
                float4 hv = *(const float4*)&rh[kk * 4];
                a0 = fmaf(hv.x, wc[4 * kk + 0], a0);
                a1 = fmaf(hv.y, wc[4 * kk + 1], a1);
                a2 = fmaf(hv.z, wc[4 * kk + 2], a2);
                a3 = fmaf(hv.w, wc[4 * kk + 3], a3);
            }
            float mv2 = (a0 + a1) + (a2 + a3);
            float hb = tanhf(c0 + mv2);
            float hf = tanhf(hb + c1);
            float hc = (1.f - c2) * hb + c2 * hf;
            float z  = zb[u];
            h[u] = (1.f - z) * hd[u] + z * hc;   // alpha==1 -> h_att = h_d
        }
        bar_lds();   // h ready for next step

        c0 = n0; c1 = n1; c2 = n2;
    }
    if (tid < U_) h_out[(size_t)b * U_ + tid] = h[tid];
}

// ---------------------------------------------------------------------------
__global__ __launch_bounds__(256) void k4a_logits(
    const float* __restrict__ h, const float* __restrict__ W_out,
    const float* __restrict__ b_out, float* __restrict__ logits)
{
    __shared__ float hs[32][U_];
    const int rb = blockIdx.y * 32;
    const int c0 = blockIdx.x * 512;
    const int tid = threadIdx.x;

    for (int idx = tid; idx < 32 * U_; idx += 256)
        hs[idx >> 7][idx & 127] = h[(size_t)(rb + (idx >> 7)) * U_ + (idx & 127)];
    __syncthreads();

    const int c  = c0 + (tid & 127) * 4;
    const int r0 = (tid >> 7) * 16;
    if (c >= NC) return;

    float4 acc[16];
#pragma unroll
    for (int i = 0; i < 16; ++i) acc[i] = make_float4(0.f, 0.f, 0.f, 0.f);

#pragma unroll 2
    for (int k = 0; k < U_; ++k) {
        float4 w = *(const float4*)&W_out[(size_t)k * NC + c];
#pragma unroll
        for (int i = 0; i < 16; ++i) {
            float x = hs[r0 + i][k];
            acc[i].x = fmaf(x, w.x, acc[i].x);
            acc[i].y = fmaf(x, w.y, acc[i].y);
            acc[i].z = fmaf(x, w.z, acc[i].z);
            acc[i].w = fmaf(x, w.w, acc[i].w);
        }
    }
    float4 bb = *(const float4*)&b_out[c];
#pragma unroll
    for (int i = 0; i < 16; ++i) {
        float4 v;
        v.x = acc[i].x + bb.x; v.y = acc[i].y + bb.y;
        v.z = acc[i].z + bb.z; v.w = acc[i].w + bb.w;
        *(float4*)&logits[(size_t)(rb + r0 + i) * NC + c] = v;
    }
}

// ---------------------------------------------------------------------------
__global__ __launch_bounds__(256) void k4b_rowstats(
    const float* __restrict__ logits, float* __restrict__ rmax, float* __restrict__ rsum)
{
    const int r = blockIdx.x;
    const int tid = threadIdx.x;
    const float* row = logits + (size_t)r * NC;

    float m = -INFINITY, s = 0.f;
    for (int c = tid; c < NC; c += 256) {
        float x = row[c];
        float mn = fmaxf(m, x);
        s = s * expf(m - mn) + expf(x - mn);
        m = mn;
    }
    __shared__ float sm[256], ss[256];
    sm[tid] = m; ss[tid] = s;
    __syncthreads();
    for (int off = 128; off > 0; off >>= 1) {
        if (tid < off) {
            float m2 = sm[tid + off], s2 = ss[tid + off];
            float M = fmaxf(sm[tid], m2);
            ss[tid] = ss[tid] * expf(sm[tid] - M) + s2 * expf(m2 - M);
            sm[tid] = M;
        }
        __syncthreads();
    }
    if (tid == 0) { rmax[r] = sm[0]; rsum[r] = ss[0]; }
}

__global__ __launch_bounds__(256) void k4c_norm(
    const float* __restrict__ logits, const float* __restrict__ rmax,
    const float* __restrict__ rsum, float* __restrict__ out)
{
    const int r = blockIdx.y;
    const int c = blockIdx.x * 256 + threadIdx.x;
    if (c < NC) {
        size_t i = (size_t)r * NC + c;
        out[i] = expf(logits[i] - rmax[r]) / rsum[r];
    }
}

// ---------------------------------------------------------------------------
extern "C" void kernel_launch(void* const* d_in, const int* in_sizes, int n_in,
                              void* d_out, int out_size, void* d_ws, size_t ws_size,
                              hipStream_t stream) {
    const int*   item   = (const int*)d_in[0];
    const int*   tix    = (const int*)d_in[1];
    const int*   frq    = (const int*)d_in[2];
    const float* Ei     = (const float*)d_in[3];
    const float* Et     = (const float*)d_in[4];
    const float* Ef     = (const float*)d_in[5];
    const float* W_xr   = (const float*)d_in[6];
    const float* W_hr   = (const float*)d_in[7];
    const float* b_r    = (const float*)d_in[8];
    const float* W_xz   = (const float*)d_in[9];
    const float* W_hz   = (const float*)d_in[10];
    const float* b_z    = (const float*)d_in[11];
    const float* W_xh   = (const float*)d_in[12];
    const float* W_hh   = (const float*)d_in[13];
    const float* b_h    = (const float*)d_in[14];
    const float* W_xtg  = (const float*)d_in[15];
    const float* W_tg   = (const float*)d_in[16];
    const float* b_tg   = (const float*)d_in[17];
    const float* W_xfg  = (const float*)d_in[18];
    const float* W_fg   = (const float*)d_in[19];
    const float* b_fg   = (const float*)d_in[20];
    const float* W_delta= (const float*)d_in[21];
    const float* b_delta= (const float*)d_in[22];
    const float* W_f_dir= (const float*)d_in[23];
    const float* b_f_dir= (const float*)d_in[24];
    const float* W_psi  = (const float*)d_in[25];
    const float* b_psi  = (const float*)d_in[26];
    // d_in[27] = W_a — dead (softmax over singleton axis == 1)
    const float* W_out  = (const float*)d_in[28];
    const float* b_out  = (const float*)d_in[29];
    float* out = (float*)d_out;

    float* ws   = (float*)d_ws;
    float* PRE  = ws + PRE_OFF;
    float* LOG  = ws + LOG_OFF;
    unsigned short* WSWZ = (unsigned short*)(ws + WSWZ_OFF);
    float* HF   = ws + HF_OFF;
    float* RMAX = ws + RMAX_OFF;
    float* RSUM = ws + RSUM_OFF;

    k0_wconv<<<12, 256, 0, stream>>>(
        W_xtg, W_tg, W_xfg, W_fg, W_xr, W_xz, W_xh,
        W_delta, W_delta + 128 * 128, W_f_dir, W_psi,
        W_psi /* pad, unused: block 11 never launched (grid=12 covers 0..11) */, WSWZ);
    k12_precompute<<<NTOK / 64, 256, 0, stream>>>(
        item, tix, frq, Ei, Et, Ef,
        b_r, b_z, b_h, b_tg, b_fg, b_delta, b_f_dir, b_psi,
        WSWZ, PRE);
    k3_scan<<<B_, 384, 0, stream>>>(PRE, W_hr, W_hz, W_hh, HF);
    k4a_logits<<<dim3((NC + 511) / 512, B_ / 32), 256, 0, stream>>>(HF, W_out, b_out, LOG);
    k4b_rowstats<<<B_, 256, 0, stream>>>(LOG, RMAX, RSUM);
    k4c_norm<<<dim3((NC + 255) / 256, B_), 256, 0, stream>>>(LOG, RMAX, RSUM, out);
}